// Round 14
// baseline (109.655 us; speedup 1.0000x reference)
//
#include <hip/hip_runtime.h>
#include <hip/hip_fp16.h>
#include <math.h>

// ---------------------------------------------------------------------------
// HematoxylinFFTModel round 14 = round 13 + (a) T14 async-stage in colfft:
// Fh loads issued into registers one pass ahead (pass-0 at kernel entry,
// pass-1 right after pass-0's LDS staging) so HBM latency hides under the
// FFT phases; loop-top barrier just ds_writes held regs. (b) rowfft folds
// the Hermitian 0.5 into the hematoxylin weights (drops 16 muls/lane).
// ---------------------------------------------------------------------------

#define PI_F 3.14159265358979323846f
#define FROW 264            // F row stride in half2 (cols 0..256 live)
#define LMSTR 264           // logmag row stride in u16 (cols 0..256 live)
#define LVMAX 1.6f          // bound: lv = log2(1+mag) <= log2(2.9) < 1.6
#define QE (65535.0f / LVMAX)
#define QD (LVMAX / 65535.0f)
#define XSTR 568            // per-FFT LDS stride in float2 (MU(511)=560)
#define RS 12               // stage row stride in u16 (24B: 8B-aligned b64)

__device__ __forceinline__ int MU(int p) {
    return ((p >> 6) * 72) + (p & 56) + ((p & 7) ^ ((p >> 3) & 7));
}
// octal digit reversal: k = k2*64 + k1*8 + k0 -> k0*64 + k1*8 + k2
__device__ __forceinline__ int odrev(int k) {
    return ((k & 7) << 6) | (k & 56) | (k >> 6);
}

__device__ __forceinline__ float2 cadd(float2 a, float2 b) { return make_float2(a.x + b.x, a.y + b.y); }
__device__ __forceinline__ float2 csub(float2 a, float2 b) { return make_float2(a.x - b.x, a.y - b.y); }
__device__ __forceinline__ float2 cmul(float2 a, float2 w) {
    return make_float2(a.x * w.x - a.y * w.y, a.x * w.y + a.y * w.x);
}

// 8-point DFT, natural-in / natural-out, w8 = e^{-2pi i/8}
__device__ __forceinline__ void dft8(float2 v[8]) {
    const float s = 0.70710678118654752f;
    float2 a0 = cadd(v[0], v[4]), b0 = csub(v[0], v[4]);
    float2 a1 = cadd(v[1], v[5]), b1 = csub(v[1], v[5]);
    float2 a2 = cadd(v[2], v[6]), b2 = csub(v[2], v[6]);
    float2 a3 = cadd(v[3], v[7]), b3 = csub(v[3], v[7]);
    b1 = make_float2(s * (b1.x + b1.y), s * (b1.y - b1.x));
    b2 = make_float2(b2.y, -b2.x);
    b3 = make_float2(s * (b3.y - b3.x), -s * (b3.x + b3.y));
    float2 c0 = cadd(a0, a2), c1 = cadd(a1, a3);
    float2 d0 = csub(a0, a2), d1 = csub(a1, a3);
    d1 = make_float2(d1.y, -d1.x);
    v[0] = cadd(c0, c1); v[4] = csub(c0, c1);
    v[2] = cadd(d0, d1); v[6] = csub(d0, d1);
    float2 e0 = cadd(b0, b2), e1 = cadd(b1, b3);
    float2 f0 = csub(b0, b2), f1 = csub(b1, b3);
    f1 = make_float2(f1.y, -f1.x);
    v[1] = cadd(e0, e1); v[5] = csub(e0, e1);
    v[3] = cadd(f0, f1); v[7] = csub(f0, f1);
}

// phases 1+2 of the 512-pt wave-synchronous FFT (trailing wave_barrier)
__device__ __forceinline__ void fft512_p12(float2* Xw, const float2* TW, int lane) {
    float2 v[8];
    #pragma unroll
    for (int m = 0; m < 8; ++m) v[m] = Xw[MU(lane + (m << 6))];
    dft8(v);
    #pragma unroll
    for (int m = 1; m < 8; ++m) v[m] = cmul(v[m], TW[(lane * m) & 511]);
    #pragma unroll
    for (int m = 0; m < 8; ++m) Xw[MU((m << 6) + lane)] = v[m];
    __builtin_amdgcn_wave_barrier();
    const int b = lane >> 3, t = lane & 7;
    const int base2 = (b << 6) + t;
    #pragma unroll
    for (int m = 0; m < 8; ++m) v[m] = Xw[MU(base2 + (m << 3))];
    dft8(v);
    #pragma unroll
    for (int m = 1; m < 8; ++m) v[m] = cmul(v[m], TW[(t * m) << 3]);
    #pragma unroll
    for (int m = 0; m < 8; ++m) Xw[MU(base2 + (m << 3))] = v[m];
    __builtin_amdgcn_wave_barrier();
}

// phase 3: load contiguous-8 + dft8, results stay in v[] (no store).
// lane (b=lane>>3, t=lane&7), element j holds Z[j*64 + t*8 + b].
__device__ __forceinline__ void fft512_p3(float2* Xw, int lane, float2 v[8]) {
    const int b = lane >> 3, t = lane & 7;
    const int base3 = (b << 6) + (t << 3);
    #pragma unroll
    for (int j = 0; j < 8; ++j) v[j] = Xw[MU(base3 + j)];
    dft8(v);
}

// full FFT with final store: stored[MU(p)] = Z[odrev(p)] (rowfft, pack col)
__device__ __forceinline__ void fft512_reg(float2* Xw, const float2* TW, int lane) {
    fft512_p12(Xw, TW, lane);
    float2 v[8];
    fft512_p3(Xw, lane, v);
    const int b = lane >> 3, t = lane & 7;
    const int base3 = (b << 6) + (t << 3);
    #pragma unroll
    for (int sidx = 0; sidx < 8; ++sidx) Xw[MU(base3 + sidx)] = v[sidx];
    __builtin_amdgcn_wave_barrier();
}

__device__ __forceinline__ void hstore(float2* Xw, int c,
                                       float r0v, float g0v, float b0v,
                                       float r1v, float g1v, float b1v,
                                       float w0, float w1, float w2) {
    r0v = fminf(fmaxf(r0v, 1e-6f), 1.0f);
    g0v = fminf(fmaxf(g0v, 1e-6f), 1.0f);
    b0v = fminf(fmaxf(b0v, 1e-6f), 1.0f);
    r1v = fminf(fmaxf(r1v, 1e-6f), 1.0f);
    g1v = fminf(fmaxf(g1v, 1e-6f), 1.0f);
    b1v = fminf(fmaxf(b1v, 1e-6f), 1.0f);
    float h0 = fmaxf(w0 * __log2f(r0v) + w1 * __log2f(g0v) + w2 * __log2f(b0v), 0.0f);
    float h1 = fmaxf(w0 * __log2f(r1v) + w1 * __log2f(g1v) + w2 * __log2f(b1v), 0.0f);
    Xw[MU(c)] = make_float2(h0, h1);     // natural order (DIF input)
}

// Pass 1: hematoxylin + packed row-pair FFT, 4 waves = 4 FFTs (8 rows)/block.
// Weights carry the Hermitian 0.5 (unpack is pure add/sub).
__global__ __launch_bounds__(256) void k_rowfft(const float* __restrict__ x,
                                                __half2* __restrict__ Fh,
                                                float w0, float w1, float w2) {
    const int b = blockIdx.x >> 6;
    const int p = blockIdx.x & 63;
    __shared__ float2 X[4 * XSTR];
    __shared__ float2 TW[512];
    const int tid = threadIdx.x;
    const int w = tid >> 6, lane = tid & 63;
    #pragma unroll
    for (int t = 0; t < 8; ++t) {
        int idx = lane + (t << 6);
        float sn, cs;
        __sincosf(-PI_F * (float)idx * (1.0f / 256.0f), &sn, &cs);
        TW[idx] = make_float2(cs, sn);      // per-wave redundant, benign
    }
    float2* Xw = X + w * XSTR;
    const float* xb = x + (size_t)b * 786432;
    const int r0 = (p << 3) + (w << 1);

    #pragma unroll
    for (int q = 0; q < 2; ++q) {
        const int cb = (q << 8) + (lane << 2);
        float4 R0 = *(const float4*)(xb +          (r0 << 9) + cb);
        float4 G0 = *(const float4*)(xb + 262144 + (r0 << 9) + cb);
        float4 B0 = *(const float4*)(xb + 524288 + (r0 << 9) + cb);
        float4 R1 = *(const float4*)(xb +          ((r0 + 1) << 9) + cb);
        float4 G1 = *(const float4*)(xb + 262144 + ((r0 + 1) << 9) + cb);
        float4 B1 = *(const float4*)(xb + 524288 + ((r0 + 1) << 9) + cb);
        hstore(Xw, cb + 0, R0.x, G0.x, B0.x, R1.x, G1.x, B1.x, w0, w1, w2);
        hstore(Xw, cb + 1, R0.y, G0.y, B0.y, R1.y, G1.y, B1.y, w0, w1, w2);
        hstore(Xw, cb + 2, R0.z, G0.z, B0.z, R1.z, G1.z, B1.z, w0, w1, w2);
        hstore(Xw, cb + 3, R0.w, G0.w, B0.w, R1.w, G1.w, B1.w, w0, w1, w2);
    }
    __builtin_amdgcn_wave_barrier();

    fft512_reg(Xw, TW, lane);

    // Hermitian unpack (0.5 pre-folded), 16B stores: lane owns k=4*lane..+3
    __half2* Fb = Fh + (size_t)b * (512 * FROW);
    {
        __half2 f0v[4], f1v[4];
        #pragma unroll
        for (int j = 0; j < 4; ++j) {
            int k = (lane << 2) + j;
            int m = (512 - k) & 511;
            float2 zk = Xw[MU(odrev(k))];
            float2 zm = Xw[MU(odrev(m))];
            f0v[j] = __floats2half2_rn(zk.x + zm.x,  zk.y - zm.y);
            f1v[j] = __floats2half2_rn(zk.y + zm.y, -(zk.x - zm.x));
        }
        *reinterpret_cast<float4*>(&Fb[r0 * FROW + (lane << 2)])       = *reinterpret_cast<float4*>(f0v);
        *reinterpret_cast<float4*>(&Fb[(r0 + 1) * FROW + (lane << 2)]) = *reinterpret_cast<float4*>(f1v);
    }
    if (lane == 0) {
        float2 z = Xw[MU(odrev(256))];
        Fb[r0 * FROW + 256]       = __floats2half2_rn(2.0f * z.x, 0.0f);   // undo: real col = 2*0.5*z
        Fb[(r0 + 1) * FROW + 256] = __floats2half2_rn(2.0f * z.y, 0.0f);
    }
}

// Pass 2: 512 threads, 8 waves; 8 columns per pass (1/wave), 2 passes.
// T14 async-stage: Fh loads issued one pass ahead into registers.
__global__ __launch_bounds__(512) void k_colfft(const __half2* __restrict__ Fh,
                                                unsigned short* __restrict__ lmu,
                                                float4* __restrict__ partials) {
    const int b = blockIdx.x >> 4;
    const int g = blockIdx.x & 15;
    __shared__ float2 X[8 * XSTR];
    __shared__ float2 TW[512];
    __shared__ unsigned short stage[512 * RS];   // [k][col], col 8 = u256
    __shared__ float4 wred[8];
    const int tid = threadIdx.x;
    const int w = tid >> 6, lane = tid & 63;
    const __half2* Fb = Fh + (size_t)b * (512 * FROW);
    const int yA = tid >> 1, yB = (tid >> 1) + 256, hh = tid & 1;

    // prefetch pass 0 into registers (overlaps TW fill + first barrier)
    float4 pfA = *(const float4*)&Fb[yA * FROW + (g << 4) + (hh << 2)];
    float4 pfB = *(const float4*)&Fb[yB * FROW + (g << 4) + (hh << 2)];
    float pf256A = 0.0f, pf256B = 0.0f;
    if (g == 0 && hh == 0) {
        pf256A = __half22float2(Fb[yA * FROW + 256]).x;
        pf256B = __half22float2(Fb[yB * FROW + 256]).x;
    }
    {
        float sn, cs;
        __sincosf(-PI_F * (float)tid * (1.0f / 256.0f), &sn, &cs);
        TW[tid] = make_float2(cs, sn);
    }
    unsigned short* lm_b = lmu + (size_t)b * (512 * LMSTR);
    float mn = 1e30f, mx = -1e30f, s1 = 0.0f, s2 = 0.0f;

    for (int pass = 0; pass < 2; ++pass) {
        const int u0 = (g << 4) + (pass << 3);
        const bool packpass = (g == 0 && pass == 0);
        __syncthreads();                // X & stage free of prev readers
        // staging from held registers
        {
            __half2 c4[4];
            *reinterpret_cast<float4*>(c4) = pfA;
            if (packpass && hh == 0) {
                float2 f0 = __half22float2(c4[0]);
                X[MU(yA)] = make_float2(f0.x, pf256A);
                #pragma unroll
                for (int j = 1; j < 4; ++j) X[j * XSTR + MU(yA)] = __half22float2(c4[j]);
            } else {
                #pragma unroll
                for (int j = 0; j < 4; ++j) X[((hh << 2) + j) * XSTR + MU(yA)] = __half22float2(c4[j]);
            }
            *reinterpret_cast<float4*>(c4) = pfB;
            if (packpass && hh == 0) {
                float2 f0 = __half22float2(c4[0]);
                X[MU(yB)] = make_float2(f0.x, pf256B);
                #pragma unroll
                for (int j = 1; j < 4; ++j) X[j * XSTR + MU(yB)] = __half22float2(c4[j]);
            } else {
                #pragma unroll
                for (int j = 0; j < 4; ++j) X[((hh << 2) + j) * XSTR + MU(yB)] = __half22float2(c4[j]);
            }
        }
        if (pass == 0) {                // issue pass-1 loads; fly under FFT
            const int u1 = (g << 4) + 8;
            pfA = *(const float4*)&Fb[yA * FROW + u1 + (hh << 2)];
            pfB = *(const float4*)&Fb[yB * FROW + u1 + (hh << 2)];
        }
        __syncthreads();
        float2* Xc = X + w * XSTR;
        fft512_p12(Xc, TW, lane);
        float2 v[8];
        fft512_p3(Xc, lane, v);
        if (!(packpass && w == 0)) {
            // fast path: lane holds Z[k], k = j*64 + t*8 + bb
            const int bb = lane >> 3, t = lane & 7;
            #pragma unroll
            for (int j = 0; j < 8; ++j) {
                int k = (j << 6) + (t << 3) + bb;
                float lv = __log2f(1.0f + sqrtf(v[j].x * v[j].x + v[j].y * v[j].y));
                unsigned q = (unsigned)__float2uint_rn(fminf(lv, LVMAX) * QE);
                stage[k * RS + w] = (unsigned short)q;
                mn = fminf(mn, lv);
                mx = fmaxf(mx, lv);
                s1 += 2.0f * lv;        // u in 1..255: mirrored, 2x weight
                s2 += 2.0f * lv * lv;
            }
        } else {
            // packed column: store + wave-local Hermitian unpack (cross-lane)
            const int bb = lane >> 3, t = lane & 7;
            const int base3 = (bb << 6) + (t << 3);
            #pragma unroll
            for (int sidx = 0; sidx < 8; ++sidx) Xc[MU(base3 + sidx)] = v[sidx];
            __builtin_amdgcn_wave_barrier();
            #pragma unroll
            for (int t2 = 0; t2 < 8; ++t2) {
                int k = lane + (t2 << 6);
                int m = (512 - k) & 511;
                float2 zk = Xc[MU(odrev(k))];
                float2 zm = Xc[MU(odrev(m))];
                float2 c0   = make_float2(0.5f * (zk.x + zm.x),  0.5f * (zk.y - zm.y));
                float2 c256 = make_float2(0.5f * (zk.y + zm.y), -0.5f * (zk.x - zm.x));
                float lv0   = __log2f(1.0f + sqrtf(c0.x * c0.x + c0.y * c0.y));
                float lv256 = __log2f(1.0f + sqrtf(c256.x * c256.x + c256.y * c256.y));
                unsigned q0 = (unsigned)__float2uint_rn(fminf(lv0,   LVMAX) * QE);
                unsigned q6 = (unsigned)__float2uint_rn(fminf(lv256, LVMAX) * QE);
                stage[k * RS + 0] = (unsigned short)q0;
                stage[k * RS + 8] = (unsigned short)q6;
                mn = fminf(mn, fminf(lv0, lv256));
                mx = fmaxf(mx, fmaxf(lv0, lv256));
                s1 += lv0 + lv256;              // u=0, u=256: counted once
                s2 += lv0 * lv0 + lv256 * lv256;
            }
        }
        __syncthreads();                // stage ready
        // coalesced copy-out: 2 threads per output row (4 u16 = 8B each)
        #pragma unroll
        for (int it = 0; it < 2; ++it) {
            int i2 = tid + (it << 9);
            int ro = i2 >> 1, h = i2 & 1;
            int k = ro ^ 256;           // fftshift
            uint2 d = *(const uint2*)&stage[k * RS + (h << 2)];
            *(uint2*)&lm_b[ro * LMSTR + u0 + (h << 2)] = d;
        }
        if (packpass) {                 // u=256 column (staging col 8)
            int ro = tid;               // 512 threads = 512 rows
            lm_b[ro * LMSTR + 256] = stage[(ro ^ 256) * RS + 8];
        }
    }

    #pragma unroll
    for (int off = 32; off > 0; off >>= 1) {
        mn = fminf(mn, __shfl_down(mn, off, 64));
        mx = fmaxf(mx, __shfl_down(mx, off, 64));
        s1 += __shfl_down(s1, off, 64);
        s2 += __shfl_down(s2, off, 64);
    }
    if (lane == 0) wred[w] = make_float4(mn, mx, s1, s2);
    __syncthreads();
    if (tid == 0) {
        float4 r = wred[0];
        #pragma unroll
        for (int wv = 1; wv < 8; ++wv) {
            float4 q2 = wred[wv];
            r.x = fminf(r.x, q2.x);
            r.y = fmaxf(r.y, q2.y);
            r.z += q2.z;
            r.w += q2.w;
        }
        partials[blockIdx.x] = r;
    }
}

// Pass 3: out = A*lv + B. 4 row-pairs per block; LDS-staged, float4 stores.
// (A,B) via parallel 16-lane partial fold published by existing barrier.
__global__ __launch_bounds__(256) void k_norm(const unsigned short* __restrict__ lmu,
                                              float* __restrict__ out,
                                              const float4* __restrict__ partials,
                                              const float* __restrict__ gamma,
                                              const float* __restrict__ beta) {
    const int j = blockIdx.x & 63;     // row-pairs p = 4j..4j+3
    const int b = blockIdx.x >> 6;
    __shared__ unsigned short L[8][260];   // 8 rows x cols 0..256 (+pad)
    __shared__ float2 sAB;
    const unsigned short* lb = lmu + (size_t)b * (512 * LMSTR);
    float* ob = out + ((size_t)b << 18);
    const int tid = threadIdx.x;

    // parallel partial fold (wave 0, lanes 0..15) — overlaps with staging
    if (tid < 16) {
        float4 r = partials[(b << 4) + tid];
        float mn = r.x, mx = r.y, s1 = r.z, s2 = r.w;
        #pragma unroll
        for (int off = 8; off > 0; off >>= 1) {
            mn = fminf(mn, __shfl_down(mn, off, 64));
            mx = fmaxf(mx, __shfl_down(mx, off, 64));
            s1 += __shfl_down(s1, off, 64);
            s2 += __shfl_down(s2, off, 64);
        }
        if (tid == 0) {
            const float N = 262144.0f;
            float mean = s1 / N;
            float var = fmaxf(s2 / N - mean * mean, 0.0f);
            float rng = mx - mn;
            float gm = gamma[0], bt = beta[0];
            float A, B;
            if (rng > 0.0f) {
                float inv = 1.0f / rng;
                float varn = var * inv * inv;
                float sc = 1.0f / sqrtf(varn + 1e-5f);
                A = gm * sc * inv;
                B = bt - mean * A;
            } else {
                A = 0.0f;
                B = bt;
            }
            sAB = make_float2(A, B);
        }
    }

    auto rowOf = [&](int row8) -> int {
        int q = row8 >> 1, h = row8 & 1;
        int p = (j << 2) + q;
        return h ? ((p == 0) ? 256 : 512 - p) : p;
    };

    // stage 8 rows x 257 u16: 64 ushort4 chunks + 1 scalar per row
    for (int i = tid; i < 8 * 65; i += 256) {
        int row8 = i / 65, c4 = i % 65;
        int r = rowOf(row8);
        const unsigned short* Ld = lb + (size_t)r * LMSTR;
        if (c4 < 64) {
            *(uint2*)&L[row8][c4 << 2] = *(const uint2*)&Ld[c4 << 2];
        } else {
            L[row8][256] = Ld[256];
        }
    }
    __syncthreads();                    // publishes L and sAB

    const float A = sAB.x, B = sAB.y;
    for (int i = tid; i < 1024; i += 256) {
        int row8 = i >> 7, f4 = i & 127;
        int co = f4 << 2;
        int r = rowOf(row8);
        int p = (j << 2) + (row8 >> 1);
        int m8 = (p == 0) ? row8 : (row8 ^ 1);   // mirror row's LDS slot
        float4 o;
        if (f4 >= 64) {                          // direct: u = co-256..+3
            int u = co - 256;
            o.x = (float)L[row8][u]     * QD * A + B;
            o.y = (float)L[row8][u + 1] * QD * A + B;
            o.z = (float)L[row8][u + 2] * QD * A + B;
            o.w = (float)L[row8][u + 3] * QD * A + B;
        } else {                                 // mirror: u' = 256-co-k
            o.x = ((co == 0) ? (float)L[row8][256]
                             : (float)L[m8][256 - co]) * QD * A + B;
            o.y = (float)L[m8][255 - co] * QD * A + B;
            o.z = (float)L[m8][254 - co] * QD * A + B;
            o.w = (float)L[m8][253 - co] * QD * A + B;
        }
        *(float4*)&ob[(r << 9) + co] = o;
    }
}

extern "C" void kernel_launch(void* const* d_in, const int* in_sizes, int n_in,
                              void* d_out, int out_size, void* d_ws, size_t ws_size,
                              hipStream_t stream) {
    const float* x     = (const float*)d_in[0];
    const float* gamma = (const float*)d_in[1];
    const float* beta  = (const float*)d_in[2];
    float* out = (float*)d_out;

    // ws: Fh (34.6 MB) | lmu (17.3 MB @40MB) | partials (@60MB)
    __half2* Fh = (__half2*)d_ws;
    unsigned short* lmu = (unsigned short*)((char*)d_ws + ((size_t)40 << 20));
    float4* partials = (float4*)((char*)d_ws + ((size_t)60 << 20));

    const double M00=0.65, M01=0.70, M02=0.29;
    const double M10=0.07, M11=0.99, M12=0.11;
    const double M20=0.27, M21=0.57, M22=0.78;
    const double det = M00*(M11*M22 - M12*M21)
                     - M01*(M10*M22 - M12*M20)
                     + M02*(M10*M21 - M11*M20);
    const float hw0 = (float)( (M11*M22 - M12*M21) / det);
    const float hw1 = (float)(-(M10*M22 - M12*M20) / det);
    const float hw2 = (float)( (M10*M21 - M11*M20) / det);
    const float invLA2 = (float)(log(2.0) / log(1e-6));
    const float sN = 1.0f / (512.0f * 512.0f);
    // 0.5 = Hermitian unpack factor, folded into h (exact in fp32)
    const float w0 = hw0 * invLA2 * sN * 0.5f;
    const float w1 = hw1 * invLA2 * sN * 0.5f;
    const float w2 = hw2 * invLA2 * sN * 0.5f;

    k_rowfft<<<64 * 64, 256, 0, stream>>>(x, Fh, w0, w1, w2);
    k_colfft<<<64 * 16, 512, 0, stream>>>(Fh, lmu, partials);
    k_norm<<<64 * 64, 256, 0, stream>>>(lmu, out, partials, gamma, beta);
}

// Round 15
// 103.792 us; speedup vs baseline: 1.0565x; 1.0565x over previous
//
#include <hip/hip_runtime.h>
#include <hip/hip_fp16.h>
#include <math.h>

// ---------------------------------------------------------------------------
// HematoxylinFFTModel round 15 = round 13 (best structure, 103.9us) with
// rowfft's Hermitian-0.5 weight fold kept (pure op removal, exact in fp32).
// Round-14's T14 register-prefetch in colfft REVERTED: pinning 2x float4
// live across staging+FFT raised colfft's sustained VGPR floor past an
// occupancy step (512-thr kernel, occupancy-critical) -> +5.7us. colfft is
// byte-identical to round 13.
// ---------------------------------------------------------------------------

#define PI_F 3.14159265358979323846f
#define FROW 264            // F row stride in half2 (cols 0..256 live)
#define LMSTR 264           // logmag row stride in u16 (cols 0..256 live)
#define LVMAX 1.6f          // bound: lv = log2(1+mag) <= log2(2.9) < 1.6
#define QE (65535.0f / LVMAX)
#define QD (LVMAX / 65535.0f)
#define XSTR 568            // per-FFT LDS stride in float2 (MU(511)=560)
#define RS 12               // stage row stride in u16 (24B: 8B-aligned b64)

__device__ __forceinline__ int MU(int p) {
    return ((p >> 6) * 72) + (p & 56) + ((p & 7) ^ ((p >> 3) & 7));
}
// octal digit reversal: k = k2*64 + k1*8 + k0 -> k0*64 + k1*8 + k2
__device__ __forceinline__ int odrev(int k) {
    return ((k & 7) << 6) | (k & 56) | (k >> 6);
}

__device__ __forceinline__ float2 cadd(float2 a, float2 b) { return make_float2(a.x + b.x, a.y + b.y); }
__device__ __forceinline__ float2 csub(float2 a, float2 b) { return make_float2(a.x - b.x, a.y - b.y); }
__device__ __forceinline__ float2 cmul(float2 a, float2 w) {
    return make_float2(a.x * w.x - a.y * w.y, a.x * w.y + a.y * w.x);
}

// 8-point DFT, natural-in / natural-out, w8 = e^{-2pi i/8}
__device__ __forceinline__ void dft8(float2 v[8]) {
    const float s = 0.70710678118654752f;
    float2 a0 = cadd(v[0], v[4]), b0 = csub(v[0], v[4]);
    float2 a1 = cadd(v[1], v[5]), b1 = csub(v[1], v[5]);
    float2 a2 = cadd(v[2], v[6]), b2 = csub(v[2], v[6]);
    float2 a3 = cadd(v[3], v[7]), b3 = csub(v[3], v[7]);
    b1 = make_float2(s * (b1.x + b1.y), s * (b1.y - b1.x));
    b2 = make_float2(b2.y, -b2.x);
    b3 = make_float2(s * (b3.y - b3.x), -s * (b3.x + b3.y));
    float2 c0 = cadd(a0, a2), c1 = cadd(a1, a3);
    float2 d0 = csub(a0, a2), d1 = csub(a1, a3);
    d1 = make_float2(d1.y, -d1.x);
    v[0] = cadd(c0, c1); v[4] = csub(c0, c1);
    v[2] = cadd(d0, d1); v[6] = csub(d0, d1);
    float2 e0 = cadd(b0, b2), e1 = cadd(b1, b3);
    float2 f0 = csub(b0, b2), f1 = csub(b1, b3);
    f1 = make_float2(f1.y, -f1.x);
    v[1] = cadd(e0, e1); v[5] = csub(e0, e1);
    v[3] = cadd(f0, f1); v[7] = csub(f0, f1);
}

// phases 1+2 of the 512-pt wave-synchronous FFT (trailing wave_barrier)
__device__ __forceinline__ void fft512_p12(float2* Xw, const float2* TW, int lane) {
    float2 v[8];
    #pragma unroll
    for (int m = 0; m < 8; ++m) v[m] = Xw[MU(lane + (m << 6))];
    dft8(v);
    #pragma unroll
    for (int m = 1; m < 8; ++m) v[m] = cmul(v[m], TW[(lane * m) & 511]);
    #pragma unroll
    for (int m = 0; m < 8; ++m) Xw[MU((m << 6) + lane)] = v[m];
    __builtin_amdgcn_wave_barrier();
    const int b = lane >> 3, t = lane & 7;
    const int base2 = (b << 6) + t;
    #pragma unroll
    for (int m = 0; m < 8; ++m) v[m] = Xw[MU(base2 + (m << 3))];
    dft8(v);
    #pragma unroll
    for (int m = 1; m < 8; ++m) v[m] = cmul(v[m], TW[(t * m) << 3]);
    #pragma unroll
    for (int m = 0; m < 8; ++m) Xw[MU(base2 + (m << 3))] = v[m];
    __builtin_amdgcn_wave_barrier();
}

// phase 3: load contiguous-8 + dft8, results stay in v[] (no store).
// lane (b=lane>>3, t=lane&7), element j holds Z[j*64 + t*8 + b].
__device__ __forceinline__ void fft512_p3(float2* Xw, int lane, float2 v[8]) {
    const int b = lane >> 3, t = lane & 7;
    const int base3 = (b << 6) + (t << 3);
    #pragma unroll
    for (int j = 0; j < 8; ++j) v[j] = Xw[MU(base3 + j)];
    dft8(v);
}

// full FFT with final store: stored[MU(p)] = Z[odrev(p)] (rowfft, pack col)
__device__ __forceinline__ void fft512_reg(float2* Xw, const float2* TW, int lane) {
    fft512_p12(Xw, TW, lane);
    float2 v[8];
    fft512_p3(Xw, lane, v);
    const int b = lane >> 3, t = lane & 7;
    const int base3 = (b << 6) + (t << 3);
    #pragma unroll
    for (int sidx = 0; sidx < 8; ++sidx) Xw[MU(base3 + sidx)] = v[sidx];
    __builtin_amdgcn_wave_barrier();
}

__device__ __forceinline__ void hstore(float2* Xw, int c,
                                       float r0v, float g0v, float b0v,
                                       float r1v, float g1v, float b1v,
                                       float w0, float w1, float w2) {
    r0v = fminf(fmaxf(r0v, 1e-6f), 1.0f);
    g0v = fminf(fmaxf(g0v, 1e-6f), 1.0f);
    b0v = fminf(fmaxf(b0v, 1e-6f), 1.0f);
    r1v = fminf(fmaxf(r1v, 1e-6f), 1.0f);
    g1v = fminf(fmaxf(g1v, 1e-6f), 1.0f);
    b1v = fminf(fmaxf(b1v, 1e-6f), 1.0f);
    float h0 = fmaxf(w0 * __log2f(r0v) + w1 * __log2f(g0v) + w2 * __log2f(b0v), 0.0f);
    float h1 = fmaxf(w0 * __log2f(r1v) + w1 * __log2f(g1v) + w2 * __log2f(b1v), 0.0f);
    Xw[MU(c)] = make_float2(h0, h1);     // natural order (DIF input)
}

// Pass 1: hematoxylin + packed row-pair FFT, 4 waves = 4 FFTs (8 rows)/block.
// Weights carry the Hermitian 0.5 (unpack is pure add/sub).
__global__ __launch_bounds__(256) void k_rowfft(const float* __restrict__ x,
                                                __half2* __restrict__ Fh,
                                                float w0, float w1, float w2) {
    const int b = blockIdx.x >> 6;
    const int p = blockIdx.x & 63;
    __shared__ float2 X[4 * XSTR];
    __shared__ float2 TW[512];
    const int tid = threadIdx.x;
    const int w = tid >> 6, lane = tid & 63;
    #pragma unroll
    for (int t = 0; t < 8; ++t) {
        int idx = lane + (t << 6);
        float sn, cs;
        __sincosf(-PI_F * (float)idx * (1.0f / 256.0f), &sn, &cs);
        TW[idx] = make_float2(cs, sn);      // per-wave redundant, benign
    }
    float2* Xw = X + w * XSTR;
    const float* xb = x + (size_t)b * 786432;
    const int r0 = (p << 3) + (w << 1);

    #pragma unroll
    for (int q = 0; q < 2; ++q) {
        const int cb = (q << 8) + (lane << 2);
        float4 R0 = *(const float4*)(xb +          (r0 << 9) + cb);
        float4 G0 = *(const float4*)(xb + 262144 + (r0 << 9) + cb);
        float4 B0 = *(const float4*)(xb + 524288 + (r0 << 9) + cb);
        float4 R1 = *(const float4*)(xb +          ((r0 + 1) << 9) + cb);
        float4 G1 = *(const float4*)(xb + 262144 + ((r0 + 1) << 9) + cb);
        float4 B1 = *(const float4*)(xb + 524288 + ((r0 + 1) << 9) + cb);
        hstore(Xw, cb + 0, R0.x, G0.x, B0.x, R1.x, G1.x, B1.x, w0, w1, w2);
        hstore(Xw, cb + 1, R0.y, G0.y, B0.y, R1.y, G1.y, B1.y, w0, w1, w2);
        hstore(Xw, cb + 2, R0.z, G0.z, B0.z, R1.z, G1.z, B1.z, w0, w1, w2);
        hstore(Xw, cb + 3, R0.w, G0.w, B0.w, R1.w, G1.w, B1.w, w0, w1, w2);
    }
    __builtin_amdgcn_wave_barrier();

    fft512_reg(Xw, TW, lane);

    // Hermitian unpack (0.5 pre-folded), 16B stores: lane owns k=4*lane..+3
    __half2* Fb = Fh + (size_t)b * (512 * FROW);
    {
        __half2 f0v[4], f1v[4];
        #pragma unroll
        for (int j = 0; j < 4; ++j) {
            int k = (lane << 2) + j;
            int m = (512 - k) & 511;
            float2 zk = Xw[MU(odrev(k))];
            float2 zm = Xw[MU(odrev(m))];
            f0v[j] = __floats2half2_rn(zk.x + zm.x,  zk.y - zm.y);
            f1v[j] = __floats2half2_rn(zk.y + zm.y, -(zk.x - zm.x));
        }
        *reinterpret_cast<float4*>(&Fb[r0 * FROW + (lane << 2)])       = *reinterpret_cast<float4*>(f0v);
        *reinterpret_cast<float4*>(&Fb[(r0 + 1) * FROW + (lane << 2)]) = *reinterpret_cast<float4*>(f1v);
    }
    if (lane == 0) {
        float2 z = Xw[MU(odrev(256))];
        Fb[r0 * FROW + 256]       = __floats2half2_rn(2.0f * z.x, 0.0f);   // real col = 2*(0.5*z)
        Fb[(r0 + 1) * FROW + 256] = __floats2half2_rn(2.0f * z.y, 0.0f);
    }
}

// Pass 2: 512 threads, 8 waves; 8 columns per pass (1/wave), 2 passes.
// In-register magnitude after phase 3; u16 staging; coalesced copy-out.
// (round-13 form: loads issued in-loop, short live ranges)
__global__ __launch_bounds__(512) void k_colfft(const __half2* __restrict__ Fh,
                                                unsigned short* __restrict__ lmu,
                                                float4* __restrict__ partials) {
    const int b = blockIdx.x >> 4;
    const int g = blockIdx.x & 15;
    __shared__ float2 X[8 * XSTR];
    __shared__ float2 TW[512];
    __shared__ unsigned short stage[512 * RS];   // [k][col], col 8 = u256
    __shared__ float4 wred[8];
    const int tid = threadIdx.x;
    const int w = tid >> 6, lane = tid & 63;
    {
        float sn, cs;
        __sincosf(-PI_F * (float)tid * (1.0f / 256.0f), &sn, &cs);
        TW[tid] = make_float2(cs, sn);
    }
    const __half2* Fb = Fh + (size_t)b * (512 * FROW);
    unsigned short* lm_b = lmu + (size_t)b * (512 * LMSTR);
    float mn = 1e30f, mx = -1e30f, s1 = 0.0f, s2 = 0.0f;

    for (int pass = 0; pass < 2; ++pass) {
        const int u0 = (g << 4) + (pass << 3);
        const bool packpass = (g == 0 && pass == 0);
        __syncthreads();                // X & stage free of prev readers
        // staging: 2 threads/row, one float4 (4 half2 = 4 columns) each
        for (int i = tid; i < 1024; i += 512) {
            int y = i >> 1, h = i & 1;
            __half2 c4[4];
            *reinterpret_cast<float4*>(c4) =
                *reinterpret_cast<const float4*>(&Fb[y * FROW + u0 + (h << 2)]);
            if (packpass && h == 0) {
                // packed DC/Nyquist column: z = F[y][0].re + i*F[y][256].re
                float f256 = __half22float2(Fb[y * FROW + 256]).x;
                float2 f0 = __half22float2(c4[0]);
                X[MU(y)] = make_float2(f0.x, f256);
                #pragma unroll
                for (int j = 1; j < 4; ++j)
                    X[j * XSTR + MU(y)] = __half22float2(c4[j]);
            } else {
                #pragma unroll
                for (int j = 0; j < 4; ++j)
                    X[((h << 2) + j) * XSTR + MU(y)] = __half22float2(c4[j]);
            }
        }
        __syncthreads();
        float2* Xc = X + w * XSTR;
        fft512_p12(Xc, TW, lane);
        float2 v[8];
        fft512_p3(Xc, lane, v);
        if (!(packpass && w == 0)) {
            // fast path: lane holds Z[k], k = j*64 + t*8 + bb
            const int bb = lane >> 3, t = lane & 7;
            #pragma unroll
            for (int j = 0; j < 8; ++j) {
                int k = (j << 6) + (t << 3) + bb;
                float lv = __log2f(1.0f + sqrtf(v[j].x * v[j].x + v[j].y * v[j].y));
                unsigned q = (unsigned)__float2uint_rn(fminf(lv, LVMAX) * QE);
                stage[k * RS + w] = (unsigned short)q;
                mn = fminf(mn, lv);
                mx = fmaxf(mx, lv);
                s1 += 2.0f * lv;        // u in 1..255: mirrored, 2x weight
                s2 += 2.0f * lv * lv;
            }
        } else {
            // packed column: store + wave-local Hermitian unpack (cross-lane)
            const int bb = lane >> 3, t = lane & 7;
            const int base3 = (bb << 6) + (t << 3);
            #pragma unroll
            for (int sidx = 0; sidx < 8; ++sidx) Xc[MU(base3 + sidx)] = v[sidx];
            __builtin_amdgcn_wave_barrier();
            #pragma unroll
            for (int t2 = 0; t2 < 8; ++t2) {
                int k = lane + (t2 << 6);
                int m = (512 - k) & 511;
                float2 zk = Xc[MU(odrev(k))];
                float2 zm = Xc[MU(odrev(m))];
                float2 c0   = make_float2(0.5f * (zk.x + zm.x),  0.5f * (zk.y - zm.y));
                float2 c256 = make_float2(0.5f * (zk.y + zm.y), -0.5f * (zk.x - zm.x));
                float lv0   = __log2f(1.0f + sqrtf(c0.x * c0.x + c0.y * c0.y));
                float lv256 = __log2f(1.0f + sqrtf(c256.x * c256.x + c256.y * c256.y));
                unsigned q0 = (unsigned)__float2uint_rn(fminf(lv0,   LVMAX) * QE);
                unsigned q6 = (unsigned)__float2uint_rn(fminf(lv256, LVMAX) * QE);
                stage[k * RS + 0] = (unsigned short)q0;
                stage[k * RS + 8] = (unsigned short)q6;
                mn = fminf(mn, fminf(lv0, lv256));
                mx = fmaxf(mx, fmaxf(lv0, lv256));
                s1 += lv0 + lv256;              // u=0, u=256: counted once
                s2 += lv0 * lv0 + lv256 * lv256;
            }
        }
        __syncthreads();                // stage ready
        // coalesced copy-out: 2 threads per output row (4 u16 = 8B each)
        #pragma unroll
        for (int it = 0; it < 2; ++it) {
            int i2 = tid + (it << 9);
            int ro = i2 >> 1, h = i2 & 1;
            int k = ro ^ 256;           // fftshift
            uint2 d = *(const uint2*)&stage[k * RS + (h << 2)];
            *(uint2*)&lm_b[ro * LMSTR + u0 + (h << 2)] = d;
        }
        if (packpass) {                 // u=256 column (staging col 8)
            int ro = tid;               // 512 threads = 512 rows
            lm_b[ro * LMSTR + 256] = stage[(ro ^ 256) * RS + 8];
        }
    }

    #pragma unroll
    for (int off = 32; off > 0; off >>= 1) {
        mn = fminf(mn, __shfl_down(mn, off, 64));
        mx = fmaxf(mx, __shfl_down(mx, off, 64));
        s1 += __shfl_down(s1, off, 64);
        s2 += __shfl_down(s2, off, 64);
    }
    if (lane == 0) wred[w] = make_float4(mn, mx, s1, s2);
    __syncthreads();
    if (tid == 0) {
        float4 r = wred[0];
        #pragma unroll
        for (int wv = 1; wv < 8; ++wv) {
            float4 q2 = wred[wv];
            r.x = fminf(r.x, q2.x);
            r.y = fmaxf(r.y, q2.y);
            r.z += q2.z;
            r.w += q2.w;
        }
        partials[blockIdx.x] = r;
    }
}

// Pass 3: out = A*lv + B. 4 row-pairs per block; LDS-staged, float4 stores.
// (A,B) via parallel 16-lane partial fold published by existing barrier.
__global__ __launch_bounds__(256) void k_norm(const unsigned short* __restrict__ lmu,
                                              float* __restrict__ out,
                                              const float4* __restrict__ partials,
                                              const float* __restrict__ gamma,
                                              const float* __restrict__ beta) {
    const int j = blockIdx.x & 63;     // row-pairs p = 4j..4j+3
    const int b = blockIdx.x >> 6;
    __shared__ unsigned short L[8][260];   // 8 rows x cols 0..256 (+pad)
    __shared__ float2 sAB;
    const unsigned short* lb = lmu + (size_t)b * (512 * LMSTR);
    float* ob = out + ((size_t)b << 18);
    const int tid = threadIdx.x;

    // parallel partial fold (wave 0, lanes 0..15) — overlaps with staging
    if (tid < 16) {
        float4 r = partials[(b << 4) + tid];
        float mn = r.x, mx = r.y, s1 = r.z, s2 = r.w;
        #pragma unroll
        for (int off = 8; off > 0; off >>= 1) {
            mn = fminf(mn, __shfl_down(mn, off, 64));
            mx = fmaxf(mx, __shfl_down(mx, off, 64));
            s1 += __shfl_down(s1, off, 64);
            s2 += __shfl_down(s2, off, 64);
        }
        if (tid == 0) {
            const float N = 262144.0f;
            float mean = s1 / N;
            float var = fmaxf(s2 / N - mean * mean, 0.0f);
            float rng = mx - mn;
            float gm = gamma[0], bt = beta[0];
            float A, B;
            if (rng > 0.0f) {
                float inv = 1.0f / rng;
                float varn = var * inv * inv;
                float sc = 1.0f / sqrtf(varn + 1e-5f);
                A = gm * sc * inv;
                B = bt - mean * A;
            } else {
                A = 0.0f;
                B = bt;
            }
            sAB = make_float2(A, B);
        }
    }

    auto rowOf = [&](int row8) -> int {
        int q = row8 >> 1, h = row8 & 1;
        int p = (j << 2) + q;
        return h ? ((p == 0) ? 256 : 512 - p) : p;
    };

    // stage 8 rows x 257 u16: 64 ushort4 chunks + 1 scalar per row
    for (int i = tid; i < 8 * 65; i += 256) {
        int row8 = i / 65, c4 = i % 65;
        int r = rowOf(row8);
        const unsigned short* Ld = lb + (size_t)r * LMSTR;
        if (c4 < 64) {
            *(uint2*)&L[row8][c4 << 2] = *(const uint2*)&Ld[c4 << 2];
        } else {
            L[row8][256] = Ld[256];
        }
    }
    __syncthreads();                    // publishes L and sAB

    const float A = sAB.x, B = sAB.y;
    for (int i = tid; i < 1024; i += 256) {
        int row8 = i >> 7, f4 = i & 127;
        int co = f4 << 2;
        int r = rowOf(row8);
        int p = (j << 2) + (row8 >> 1);
        int m8 = (p == 0) ? row8 : (row8 ^ 1);   // mirror row's LDS slot
        float4 o;
        if (f4 >= 64) {                          // direct: u = co-256..+3
            int u = co - 256;
            o.x = (float)L[row8][u]     * QD * A + B;
            o.y = (float)L[row8][u + 1] * QD * A + B;
            o.z = (float)L[row8][u + 2] * QD * A + B;
            o.w = (float)L[row8][u + 3] * QD * A + B;
        } else {                                 // mirror: u' = 256-co-k
            o.x = ((co == 0) ? (float)L[row8][256]
                             : (float)L[m8][256 - co]) * QD * A + B;
            o.y = (float)L[m8][255 - co] * QD * A + B;
            o.z = (float)L[m8][254 - co] * QD * A + B;
            o.w = (float)L[m8][253 - co] * QD * A + B;
        }
        *(float4*)&ob[(r << 9) + co] = o;
    }
}

extern "C" void kernel_launch(void* const* d_in, const int* in_sizes, int n_in,
                              void* d_out, int out_size, void* d_ws, size_t ws_size,
                              hipStream_t stream) {
    const float* x     = (const float*)d_in[0];
    const float* gamma = (const float*)d_in[1];
    const float* beta  = (const float*)d_in[2];
    float* out = (float*)d_out;

    // ws: Fh (34.6 MB) | lmu (17.3 MB @40MB) | partials (@60MB)
    __half2* Fh = (__half2*)d_ws;
    unsigned short* lmu = (unsigned short*)((char*)d_ws + ((size_t)40 << 20));
    float4* partials = (float4*)((char*)d_ws + ((size_t)60 << 20));

    const double M00=0.65, M01=0.70, M02=0.29;
    const double M10=0.07, M11=0.99, M12=0.11;
    const double M20=0.27, M21=0.57, M22=0.78;
    const double det = M00*(M11*M22 - M12*M21)
                     - M01*(M10*M22 - M12*M20)
                     + M02*(M10*M21 - M11*M20);
    const float hw0 = (float)( (M11*M22 - M12*M21) / det);
    const float hw1 = (float)(-(M10*M22 - M12*M20) / det);
    const float hw2 = (float)( (M10*M21 - M11*M20) / det);
    const float invLA2 = (float)(log(2.0) / log(1e-6));
    const float sN = 1.0f / (512.0f * 512.0f);
    // 0.5 = Hermitian unpack factor, folded into h (exact in fp32)
    const float w0 = hw0 * invLA2 * sN * 0.5f;
    const float w1 = hw1 * invLA2 * sN * 0.5f;
    const float w2 = hw2 * invLA2 * sN * 0.5f;

    k_rowfft<<<64 * 64, 256, 0, stream>>>(x, Fh, w0, w1, w2);
    k_colfft<<<64 * 16, 512, 0, stream>>>(Fh, lmu, partials);
    k_norm<<<64 * 64, 256, 0, stream>>>(lmu, out, partials, gamma, beta);
}